// Round 3
// baseline (150.588 us; speedup 1.0000x reference)
//
#include <hip/hip_runtime.h>
#include <math.h>

#define NFULL 4096   // DCT length per row
#define NH    2048   // half-size complex FFT
#define T     256    // threads per block

__device__ __forceinline__ int pad(int i) { return i + (i >> 3); }

__device__ __forceinline__ float2 cmul(float2 a, float2 b) {
    return make_float2(a.x * b.x - a.y * b.y, a.x * b.y + a.y * b.x);
}

// 8-point DFT, no twiddles
__device__ __forceinline__ void dft8(float2 v[8]) {
    const float s = 0.70710678118654752f;
    float2 e0 = v[0], o0 = v[1], e1 = v[2], o1 = v[3];
    float2 e2 = v[4], o2 = v[5], e3 = v[6], o3 = v[7];
    float2 t0 = make_float2(e0.x + e2.x, e0.y + e2.y);
    float2 t1 = make_float2(e0.x - e2.x, e0.y - e2.y);
    float2 t2 = make_float2(e1.x + e3.x, e1.y + e3.y);
    float2 t3 = make_float2(e1.x - e3.x, e1.y - e3.y);
    float2 E0 = make_float2(t0.x + t2.x, t0.y + t2.y);
    float2 E2 = make_float2(t0.x - t2.x, t0.y - t2.y);
    float2 E1 = make_float2(t1.x + t3.y, t1.y - t3.x);
    float2 E3 = make_float2(t1.x - t3.y, t1.y + t3.x);
    float2 u0 = make_float2(o0.x + o2.x, o0.y + o2.y);
    float2 u1 = make_float2(o0.x - o2.x, o0.y - o2.y);
    float2 u2 = make_float2(o1.x + o3.x, o1.y + o3.y);
    float2 u3 = make_float2(o1.x - o3.x, o1.y - o3.y);
    float2 O0 = make_float2(u0.x + u2.x, u0.y + u2.y);
    float2 O2 = make_float2(u0.x - u2.x, u0.y - u2.y);
    float2 O1 = make_float2(u1.x + u3.y, u1.y - u3.x);
    float2 O3 = make_float2(u1.x - u3.y, u1.y + u3.x);
    O1 = make_float2(s * (O1.x + O1.y), s * (O1.y - O1.x));
    O2 = make_float2(O2.y, -O2.x);
    O3 = make_float2(s * (O3.y - O3.x), s * (-O3.x - O3.y));
    v[0] = make_float2(E0.x + O0.x, E0.y + O0.y);
    v[4] = make_float2(E0.x - O0.x, E0.y - O0.y);
    v[1] = make_float2(E1.x + O1.x, E1.y + O1.y);
    v[5] = make_float2(E1.x - O1.x, E1.y - O1.y);
    v[2] = make_float2(E2.x + O2.x, E2.y + O2.y);
    v[6] = make_float2(E2.x - O2.x, E2.y - O2.y);
    v[3] = make_float2(E3.x + O3.x, E3.y + O3.y);
    v[7] = make_float2(E3.x - O3.x, E3.y - O3.y);
}

__device__ __forceinline__ void dft4(float2 v[4]) {
    float2 t0 = make_float2(v[0].x + v[2].x, v[0].y + v[2].y);
    float2 t1 = make_float2(v[0].x - v[2].x, v[0].y - v[2].y);
    float2 t2 = make_float2(v[1].x + v[3].x, v[1].y + v[3].y);
    float2 t3 = make_float2(v[1].x - v[3].x, v[1].y - v[3].y);
    v[0] = make_float2(t0.x + t2.x, t0.y + t2.y);
    v[2] = make_float2(t0.x - t2.x, t0.y - t2.y);
    v[1] = make_float2(t1.x + t3.y, t1.y - t3.x);
    v[3] = make_float2(t1.x - t3.y, t1.y + t3.x);
}

// tw[k] = exp(-2*pi*i*k/4096), k = 0..4095
__global__ __launch_bounds__(256) void init_tw(float2* __restrict__ tw) {
    int k = blockIdx.x * 256 + threadIdx.x;
    float ang = -2.0f * (float)M_PI * (float)k / 4096.0f;
    float s, c;
    sincosf(ang, &s, &c);
    tw[k] = make_float2(c, s);
}

// DCT-II row pass: Makhoul perm + real-packed 2048-pt Stockham FFT (radix 8,8,8,4),
// single LDS buffer (read-all / barrier / write-all), twiddles from global table.
__global__ __launch_bounds__(T, 6) void dct_rows_rfft(const float* __restrict__ in,
                                                      const float* __restrict__ expk,
                                                      const float2* __restrict__ tw,
                                                      float* __restrict__ out) {
    __shared__ float2 A[NH + (NH >> 3)];
    const int row = blockIdx.x;
    const int t = threadIdx.x;
    const float4* __restrict__ src4 = (const float4*)(in + (size_t)row * NFULL);

    // load + Makhoul permute + real pack: z[c] = (x[4c], x[4c+2]), z[2047-c] = (x[4c+3], x[4c+1])
    #pragma unroll
    for (int i = 0; i < 4; ++i) {
        int c = t + T * i;
        float4 f = src4[c];
        A[pad(c)]        = make_float2(f.x, f.z);
        A[pad(2047 - c)] = make_float2(f.w, f.y);
    }
    __syncthreads();

    float2 v[8];
    // stage 1: R=8, Ns=1 (no twiddles)
    {
        const int j = t;
        #pragma unroll
        for (int r = 0; r < 8; ++r) v[r] = A[pad(j + 256 * r)];
        __syncthreads();
        dft8(v);
        #pragma unroll
        for (int r = 0; r < 8; ++r) A[pad(8 * j + r)] = v[r];
        __syncthreads();
    }
    // stage 2: R=8, Ns=8; w^r = tw[64*(j&7)*r]
    {
        const int j = t;
        const int m = 64 * (j & 7);
        #pragma unroll
        for (int r = 0; r < 8; ++r) v[r] = A[pad(j + 256 * r)];
        float2 w1 = tw[m], w2 = tw[2 * m], w3 = tw[3 * m];
        float2 w4 = tw[4 * m], w5 = tw[5 * m], w6 = tw[6 * m], w7 = tw[7 * m];
        __syncthreads();
        v[1] = cmul(v[1], w1); v[2] = cmul(v[2], w2); v[3] = cmul(v[3], w3);
        v[4] = cmul(v[4], w4); v[5] = cmul(v[5], w5); v[6] = cmul(v[6], w6);
        v[7] = cmul(v[7], w7);
        dft8(v);
        const int d = ((j >> 3) << 6) + (j & 7);
        #pragma unroll
        for (int r = 0; r < 8; ++r) A[pad(d + 8 * r)] = v[r];
        __syncthreads();
    }
    // stage 3: R=8, Ns=64; w^r = tw[8*(j&63)*r]
    {
        const int j = t;
        const int m = 8 * (j & 63);
        #pragma unroll
        for (int r = 0; r < 8; ++r) v[r] = A[pad(j + 256 * r)];
        float2 w1 = tw[m], w2 = tw[2 * m], w3 = tw[3 * m];
        float2 w4 = tw[4 * m], w5 = tw[5 * m], w6 = tw[6 * m], w7 = tw[7 * m];
        __syncthreads();
        v[1] = cmul(v[1], w1); v[2] = cmul(v[2], w2); v[3] = cmul(v[3], w3);
        v[4] = cmul(v[4], w4); v[5] = cmul(v[5], w5); v[6] = cmul(v[6], w6);
        v[7] = cmul(v[7], w7);
        dft8(v);
        const int d = ((j >> 6) << 9) + (j & 63);
        #pragma unroll
        for (int r = 0; r < 8; ++r) A[pad(d + 64 * r)] = v[r];
        __syncthreads();
    }
    // stage 4: R=4, Ns=512, two halves; in-place per half (disjoint read/write sets)
    #pragma unroll
    for (int h = 0; h < 2; ++h) {
        const int j = t + 256 * h;
        float2 u[4];
        #pragma unroll
        for (int r = 0; r < 4; ++r) u[r] = A[pad(j + 512 * r)];
        float2 w1 = tw[2 * j];
        float2 w2 = tw[4 * j];
        float2 w3 = tw[(6 * j) & 4095];
        u[1] = cmul(u[1], w1);
        u[2] = cmul(u[2], w2);
        u[3] = cmul(u[3], w3);
        dft4(u);
        #pragma unroll
        for (int r = 0; r < 4; ++r) A[pad(j + 512 * r)] = u[r];
    }
    __syncthreads();

    // epilogue: rfft untangle + DCT twiddle; uu = e^{-i pi k/2048} = tw[k]
    const float2* __restrict__ ek = (const float2*)expk;
    float* __restrict__ dst = out + (size_t)row * NFULL;
    #pragma unroll
    for (int i = 0; i < 8; ++i) {
        const int k = t + T * i;
        if (k == 0) {
            float2 z0 = A[pad(0)];
            dst[0]  = ek[0].x * (z0.x + z0.y);
            dst[NH] = ek[NH].x * (z0.x - z0.y);
        } else {
            float2 Zk = A[pad(k)];
            float2 Zr = A[pad(NH - k)];
            float2 E = make_float2(0.5f * (Zk.x + Zr.x), 0.5f * (Zk.y - Zr.y));
            float2 O = make_float2(0.5f * (Zk.y + Zr.y), 0.5f * (Zr.x - Zk.x));
            float2 uu = tw[k];
            float2 Y = make_float2(E.x + uu.x * O.x - uu.y * O.y,
                                   E.y + uu.x * O.y + uu.y * O.x);
            float2 wk = ek[k];
            dst[k] = wk.x * Y.x - wk.y * Y.y;
            float2 wn = ek[NFULL - k];
            dst[NFULL - k] = wn.x * Y.x + wn.y * Y.y;
        }
    }
}

// 32x32 LDS-tiled transpose
__global__ __launch_bounds__(256) void transpose4k(const float* __restrict__ in,
                                                   float* __restrict__ out) {
    __shared__ float tile[32][33];
    const int x0 = blockIdx.x * 32;
    const int y0 = blockIdx.y * 32;
    const int tx = threadIdx.x & 31;
    const int ty = threadIdx.x >> 5;

    #pragma unroll
    for (int i = 0; i < 32; i += 8)
        tile[ty + i][tx] = in[(size_t)(y0 + ty + i) * NFULL + (x0 + tx)];
    __syncthreads();
    #pragma unroll
    for (int i = 0; i < 32; i += 8)
        out[(size_t)(x0 + ty + i) * NFULL + (y0 + tx)] = tile[tx][ty + i];
}

extern "C" void kernel_launch(void* const* d_in, const int* in_sizes, int n_in,
                              void* d_out, int out_size, void* d_ws, size_t ws_size,
                              hipStream_t stream) {
    const float* x     = (const float*)d_in[0];
    const float* expkM = (const float*)d_in[1];
    const float* expkN = (const float*)d_in[2];
    float* out = (float*)d_out;
    float* ws1 = (float*)d_ws;                                   // 64 MiB matrix scratch
    float2* tw = (float2*)((char*)d_ws + (size_t)NFULL * NFULL * 4);  // +32 KB table (ws is 256 MiB)

    init_tw<<<16, 256, 0, stream>>>(tw);
    dct_rows_rfft<<<NFULL, T, 0, stream>>>(x, expkN, tw, ws1);
    transpose4k<<<dim3(128, 128), 256, 0, stream>>>(ws1, out);
    dct_rows_rfft<<<NFULL, T, 0, stream>>>(out, expkM, tw, ws1);
    transpose4k<<<dim3(128, 128), 256, 0, stream>>>(ws1, out);
}

// Round 4
// 146.105 us; speedup vs baseline: 1.0307x; 1.0307x over previous
//
#include <hip/hip_runtime.h>
#include <math.h>

#define NFULL 4096   // DCT length per row
#define NH    2048   // half-size complex FFT
#define T     256    // threads per block

__device__ __forceinline__ int pad(int i) { return i + (i >> 3); }

__device__ __forceinline__ float2 cmul(float2 a, float2 b) {
    return make_float2(a.x * b.x - a.y * b.y, a.x * b.y + a.y * b.x);
}

// 8-point DFT, no twiddles
__device__ __forceinline__ void dft8(float2 v[8]) {
    const float s = 0.70710678118654752f;
    float2 e0 = v[0], o0 = v[1], e1 = v[2], o1 = v[3];
    float2 e2 = v[4], o2 = v[5], e3 = v[6], o3 = v[7];
    float2 t0 = make_float2(e0.x + e2.x, e0.y + e2.y);
    float2 t1 = make_float2(e0.x - e2.x, e0.y - e2.y);
    float2 t2 = make_float2(e1.x + e3.x, e1.y + e3.y);
    float2 t3 = make_float2(e1.x - e3.x, e1.y - e3.y);
    float2 E0 = make_float2(t0.x + t2.x, t0.y + t2.y);
    float2 E2 = make_float2(t0.x - t2.x, t0.y - t2.y);
    float2 E1 = make_float2(t1.x + t3.y, t1.y - t3.x);
    float2 E3 = make_float2(t1.x - t3.y, t1.y + t3.x);
    float2 u0 = make_float2(o0.x + o2.x, o0.y + o2.y);
    float2 u1 = make_float2(o0.x - o2.x, o0.y - o2.y);
    float2 u2 = make_float2(o1.x + o3.x, o1.y + o3.y);
    float2 u3 = make_float2(o1.x - o3.x, o1.y - o3.y);
    float2 O0 = make_float2(u0.x + u2.x, u0.y + u2.y);
    float2 O2 = make_float2(u0.x - u2.x, u0.y - u2.y);
    float2 O1 = make_float2(u1.x + u3.y, u1.y - u3.x);
    float2 O3 = make_float2(u1.x - u3.y, u1.y + u3.x);
    O1 = make_float2(s * (O1.x + O1.y), s * (O1.y - O1.x));
    O2 = make_float2(O2.y, -O2.x);
    O3 = make_float2(s * (O3.y - O3.x), s * (-O3.x - O3.y));
    v[0] = make_float2(E0.x + O0.x, E0.y + O0.y);
    v[4] = make_float2(E0.x - O0.x, E0.y - O0.y);
    v[1] = make_float2(E1.x + O1.x, E1.y + O1.y);
    v[5] = make_float2(E1.x - O1.x, E1.y - O1.y);
    v[2] = make_float2(E2.x + O2.x, E2.y + O2.y);
    v[6] = make_float2(E2.x - O2.x, E2.y - O2.y);
    v[3] = make_float2(E3.x + O3.x, E3.y + O3.y);
    v[7] = make_float2(E3.x - O3.x, E3.y - O3.y);
}

__device__ __forceinline__ void dft4(float2 v[4]) {
    float2 t0 = make_float2(v[0].x + v[2].x, v[0].y + v[2].y);
    float2 t1 = make_float2(v[0].x - v[2].x, v[0].y - v[2].y);
    float2 t2 = make_float2(v[1].x + v[3].x, v[1].y + v[3].y);
    float2 t3 = make_float2(v[1].x - v[3].x, v[1].y - v[3].y);
    v[0] = make_float2(t0.x + t2.x, t0.y + t2.y);
    v[2] = make_float2(t0.x - t2.x, t0.y - t2.y);
    v[1] = make_float2(t1.x + t3.y, t1.y - t3.x);
    v[3] = make_float2(t1.x - t3.y, t1.y + t3.x);
}

// tw[k] = exp(-2*pi*i*k/4096)
__global__ __launch_bounds__(256) void init_tw(float2* __restrict__ tw) {
    int k = blockIdx.x * 256 + threadIdx.x;
    float ang = -2.0f * (float)M_PI * (float)k / 4096.0f;
    float s, c;
    sincosf(ang, &s, &c);
    tw[k] = make_float2(c, s);
}

// DCT-II row pass: Makhoul perm + real-packed 2048-pt Stockham FFT (radix 8,8,8,4),
// ping-pong LDS buffers (ONE barrier per stage), twiddles preloaded from global table.
__global__ __launch_bounds__(T, 4) void dct_rows_rfft(const float* __restrict__ in,
                                                      const float* __restrict__ expk,
                                                      const float2* __restrict__ tw,
                                                      float* __restrict__ out) {
    __shared__ float2 A[NH + (NH >> 3)];
    __shared__ float2 B[NH + (NH >> 3)];
    const int row = blockIdx.x;
    const int t = threadIdx.x;
    const float4* __restrict__ src4 = (const float4*)(in + (size_t)row * NFULL);

    // ---- issue global loads early: input row, then all stage twiddles ----
    float4 f0 = src4[t], f1 = src4[t + T], f2 = src4[t + 2 * T], f3 = src4[t + 3 * T];

    // stage-2 twiddles: w^r = tw[64*(t&7)*r]
    const int m2 = 64 * (t & 7);
    float2 s2w[8];
    #pragma unroll
    for (int r = 1; r < 8; ++r) s2w[r] = tw[m2 * r];
    // stage-3 twiddles: w^r = tw[8*(t&63)*r]
    const int m3 = 8 * (t & 63);
    float2 s3w[8];
    #pragma unroll
    for (int r = 1; r < 8; ++r) s3w[r] = tw[m3 * r];
    // stage-4 twiddles (radix-4, two halves j=t and j=t+256)
    float2 s4w[2][3];
    #pragma unroll
    for (int h = 0; h < 2; ++h) {
        int j = t + 256 * h;
        s4w[h][0] = tw[2 * j];
        s4w[h][1] = tw[4 * j];
        s4w[h][2] = tw[6 * j];
    }

    // ---- load + Makhoul permute + real pack ----
    // z[c] = (x[4c], x[4c+2]), z[2047-c] = (x[4c+3], x[4c+1])
    A[pad(t)]                = make_float2(f0.x, f0.z);
    A[pad(2047 - t)]         = make_float2(f0.w, f0.y);
    A[pad(t + T)]            = make_float2(f1.x, f1.z);
    A[pad(2047 - (t + T))]   = make_float2(f1.w, f1.y);
    A[pad(t + 2 * T)]        = make_float2(f2.x, f2.z);
    A[pad(2047 - (t + 2 * T))] = make_float2(f2.w, f2.y);
    A[pad(t + 3 * T)]        = make_float2(f3.x, f3.z);
    A[pad(2047 - (t + 3 * T))] = make_float2(f3.w, f3.y);
    __syncthreads();

    float2 v[8];
    // stage 1: R=8, Ns=1, A -> B (no twiddles)
    {
        #pragma unroll
        for (int r = 0; r < 8; ++r) v[r] = A[pad(t + 256 * r)];
        dft8(v);
        #pragma unroll
        for (int r = 0; r < 8; ++r) B[pad(8 * t + r)] = v[r];
    }
    __syncthreads();
    // stage 2: R=8, Ns=8, B -> A
    {
        #pragma unroll
        for (int r = 0; r < 8; ++r) v[r] = B[pad(t + 256 * r)];
        #pragma unroll
        for (int r = 1; r < 8; ++r) v[r] = cmul(v[r], s2w[r]);
        dft8(v);
        const int d = ((t >> 3) << 6) + (t & 7);
        #pragma unroll
        for (int r = 0; r < 8; ++r) A[pad(d + 8 * r)] = v[r];
    }
    __syncthreads();
    // stage 3: R=8, Ns=64, A -> B
    {
        #pragma unroll
        for (int r = 0; r < 8; ++r) v[r] = A[pad(t + 256 * r)];
        #pragma unroll
        for (int r = 1; r < 8; ++r) v[r] = cmul(v[r], s3w[r]);
        dft8(v);
        const int d = ((t >> 6) << 9) + (t & 63);
        #pragma unroll
        for (int r = 0; r < 8; ++r) B[pad(d + 64 * r)] = v[r];
    }
    __syncthreads();
    // stage 4: R=4, Ns=512, B -> A (two butterflies per thread, no internal barrier)
    #pragma unroll
    for (int h = 0; h < 2; ++h) {
        const int j = t + 256 * h;
        float2 u[4];
        #pragma unroll
        for (int r = 0; r < 4; ++r) u[r] = B[pad(j + 512 * r)];
        u[1] = cmul(u[1], s4w[h][0]);
        u[2] = cmul(u[2], s4w[h][1]);
        u[3] = cmul(u[3], s4w[h][2]);
        dft4(u);
        #pragma unroll
        for (int r = 0; r < 4; ++r) A[pad(j + 512 * r)] = u[r];
    }
    __syncthreads();

    // epilogue: rfft untangle + DCT twiddle; uu = e^{-i pi k/2048} = tw[k]
    const float2* __restrict__ ek = (const float2*)expk;
    float* __restrict__ dst = out + (size_t)row * NFULL;
    #pragma unroll
    for (int i = 0; i < 8; ++i) {
        const int k = t + T * i;
        if (k == 0) {
            float2 z0 = A[pad(0)];
            dst[0]  = ek[0].x * (z0.x + z0.y);
            dst[NH] = ek[NH].x * (z0.x - z0.y);
        } else {
            float2 Zk = A[pad(k)];
            float2 Zr = A[pad(NH - k)];
            float2 E = make_float2(0.5f * (Zk.x + Zr.x), 0.5f * (Zk.y - Zr.y));
            float2 O = make_float2(0.5f * (Zk.y + Zr.y), 0.5f * (Zr.x - Zk.x));
            float2 uu = tw[k];
            float2 Y = make_float2(E.x + uu.x * O.x - uu.y * O.y,
                                   E.y + uu.x * O.y + uu.y * O.x);
            float2 wk = ek[k];
            dst[k] = wk.x * Y.x - wk.y * Y.y;
            float2 wn = ek[NFULL - k];
            dst[NFULL - k] = wn.x * Y.x + wn.y * Y.y;
        }
    }
}

// 32x32 LDS-tiled transpose
__global__ __launch_bounds__(256) void transpose4k(const float* __restrict__ in,
                                                   float* __restrict__ out) {
    __shared__ float tile[32][33];
    const int x0 = blockIdx.x * 32;
    const int y0 = blockIdx.y * 32;
    const int tx = threadIdx.x & 31;
    const int ty = threadIdx.x >> 5;

    #pragma unroll
    for (int i = 0; i < 32; i += 8)
        tile[ty + i][tx] = in[(size_t)(y0 + ty + i) * NFULL + (x0 + tx)];
    __syncthreads();
    #pragma unroll
    for (int i = 0; i < 32; i += 8)
        out[(size_t)(x0 + ty + i) * NFULL + (y0 + tx)] = tile[tx][ty + i];
}

extern "C" void kernel_launch(void* const* d_in, const int* in_sizes, int n_in,
                              void* d_out, int out_size, void* d_ws, size_t ws_size,
                              hipStream_t stream) {
    const float* x     = (const float*)d_in[0];
    const float* expkM = (const float*)d_in[1];
    const float* expkN = (const float*)d_in[2];
    float* out = (float*)d_out;
    float* ws1 = (float*)d_ws;                                        // 64 MiB matrix scratch
    float2* tw = (float2*)((char*)d_ws + (size_t)NFULL * NFULL * 4);  // +32 KB table

    init_tw<<<16, 256, 0, stream>>>(tw);
    dct_rows_rfft<<<NFULL, T, 0, stream>>>(x, expkN, tw, ws1);
    transpose4k<<<dim3(128, 128), 256, 0, stream>>>(ws1, out);
    dct_rows_rfft<<<NFULL, T, 0, stream>>>(out, expkM, tw, ws1);
    transpose4k<<<dim3(128, 128), 256, 0, stream>>>(ws1, out);
}

// Round 5
// 104.052 us; speedup vs baseline: 1.4472x; 1.4042x over previous
//
#include <hip/hip_runtime.h>
#include <math.h>

#define NFULL 4096   // DCT length per row
#define NH    2048   // half-size complex FFT
#define T     256    // threads per block

__device__ __forceinline__ int pad(int i) { return i + (i >> 3); }

__device__ __forceinline__ float2 cmul(float2 a, float2 b) {
    return make_float2(a.x * b.x - a.y * b.y, a.x * b.y + a.y * b.x);
}

__device__ __forceinline__ float2 sc(float ang) {
    float s, c;
    __sincosf(ang, &s, &c);
    return make_float2(c, s);
}

// 8-point DFT, no twiddles
__device__ __forceinline__ void dft8(float2 v[8]) {
    const float s = 0.70710678118654752f;
    float2 e0 = v[0], o0 = v[1], e1 = v[2], o1 = v[3];
    float2 e2 = v[4], o2 = v[5], e3 = v[6], o3 = v[7];
    float2 t0 = make_float2(e0.x + e2.x, e0.y + e2.y);
    float2 t1 = make_float2(e0.x - e2.x, e0.y - e2.y);
    float2 t2 = make_float2(e1.x + e3.x, e1.y + e3.y);
    float2 t3 = make_float2(e1.x - e3.x, e1.y - e3.y);
    float2 E0 = make_float2(t0.x + t2.x, t0.y + t2.y);
    float2 E2 = make_float2(t0.x - t2.x, t0.y - t2.y);
    float2 E1 = make_float2(t1.x + t3.y, t1.y - t3.x);
    float2 E3 = make_float2(t1.x - t3.y, t1.y + t3.x);
    float2 u0 = make_float2(o0.x + o2.x, o0.y + o2.y);
    float2 u1 = make_float2(o0.x - o2.x, o0.y - o2.y);
    float2 u2 = make_float2(o1.x + o3.x, o1.y + o3.y);
    float2 u3 = make_float2(o1.x - o3.x, o1.y - o3.y);
    float2 O0 = make_float2(u0.x + u2.x, u0.y + u2.y);
    float2 O2 = make_float2(u0.x - u2.x, u0.y - u2.y);
    float2 O1 = make_float2(u1.x + u3.y, u1.y - u3.x);
    float2 O3 = make_float2(u1.x - u3.y, u1.y + u3.x);
    O1 = make_float2(s * (O1.x + O1.y), s * (O1.y - O1.x));
    O2 = make_float2(O2.y, -O2.x);
    O3 = make_float2(s * (O3.y - O3.x), s * (-O3.x - O3.y));
    v[0] = make_float2(E0.x + O0.x, E0.y + O0.y);
    v[4] = make_float2(E0.x - O0.x, E0.y - O0.y);
    v[1] = make_float2(E1.x + O1.x, E1.y + O1.y);
    v[5] = make_float2(E1.x - O1.x, E1.y - O1.y);
    v[2] = make_float2(E2.x + O2.x, E2.y + O2.y);
    v[6] = make_float2(E2.x - O2.x, E2.y - O2.y);
    v[3] = make_float2(E3.x + O3.x, E3.y + O3.y);
    v[7] = make_float2(E3.x - O3.x, E3.y - O3.y);
}

__device__ __forceinline__ void dft4(float2 v[4]) {
    float2 t0 = make_float2(v[0].x + v[2].x, v[0].y + v[2].y);
    float2 t1 = make_float2(v[0].x - v[2].x, v[0].y - v[2].y);
    float2 t2 = make_float2(v[1].x + v[3].x, v[1].y + v[3].y);
    float2 t3 = make_float2(v[1].x - v[3].x, v[1].y - v[3].y);
    v[0] = make_float2(t0.x + t2.x, t0.y + t2.y);
    v[2] = make_float2(t0.x - t2.x, t0.y - t2.y);
    v[1] = make_float2(t1.x + t3.y, t1.y - t3.x);
    v[3] = make_float2(t1.x - t3.y, t1.y + t3.x);
}

// DCT-II row pass: Makhoul perm + real-packed 2048-pt Stockham FFT (radix 8,8,8,4),
// ping-pong LDS (one barrier per stage), twiddles via short-chain sincos (no table:
// table gathers are uncoalesced per-lane loads and L1-thrash — measured regression).
__global__ __launch_bounds__(T) void dct_rows_rfft(const float* __restrict__ in,
                                                   const float* __restrict__ expk,
                                                   float* __restrict__ out) {
    __shared__ float2 A[NH + (NH >> 3)];
    __shared__ float2 B[NH + (NH >> 3)];
    const int row = blockIdx.x;
    const int t = threadIdx.x;
    const float4* __restrict__ src4 = (const float4*)(in + (size_t)row * NFULL);

    // coalesced input load
    float4 f0 = src4[t], f1 = src4[t + T], f2 = src4[t + 2 * T], f3 = src4[t + 3 * T];

    // Makhoul permute + real pack: z[c] = (x[4c], x[4c+2]), z[2047-c] = (x[4c+3], x[4c+1])
    A[pad(t)]                  = make_float2(f0.x, f0.z);
    A[pad(2047 - t)]           = make_float2(f0.w, f0.y);
    A[pad(t + T)]              = make_float2(f1.x, f1.z);
    A[pad(2047 - (t + T))]     = make_float2(f1.w, f1.y);
    A[pad(t + 2 * T)]          = make_float2(f2.x, f2.z);
    A[pad(2047 - (t + 2 * T))] = make_float2(f2.w, f2.y);
    A[pad(t + 3 * T)]          = make_float2(f3.x, f3.z);
    A[pad(2047 - (t + 3 * T))] = make_float2(f3.w, f3.y);
    __syncthreads();

    float2 v[8];
    // stage 1: R=8, Ns=1, A -> B (no twiddles)
    {
        #pragma unroll
        for (int r = 0; r < 8; ++r) v[r] = A[pad(t + 256 * r)];
        dft8(v);
        #pragma unroll
        for (int r = 0; r < 8; ++r) B[pad(8 * t + r)] = v[r];
    }
    __syncthreads();
    // stage 2: R=8, Ns=8, B -> A; w^r = e^{-i pi (t&7) r / 32}
    {
        #pragma unroll
        for (int r = 0; r < 8; ++r) v[r] = B[pad(t + 256 * r)];
        const float a = -(float)M_PI / 32.0f * (float)(t & 7);
        float2 w1 = sc(a), w2 = sc(2.0f * a), w4 = sc(4.0f * a);
        float2 w3 = cmul(w1, w2), w5 = cmul(w1, w4), w6 = cmul(w2, w4);
        float2 w7 = cmul(w3, w4);
        v[1] = cmul(v[1], w1); v[2] = cmul(v[2], w2); v[3] = cmul(v[3], w3);
        v[4] = cmul(v[4], w4); v[5] = cmul(v[5], w5); v[6] = cmul(v[6], w6);
        v[7] = cmul(v[7], w7);
        dft8(v);
        const int d = ((t >> 3) << 6) + (t & 7);
        #pragma unroll
        for (int r = 0; r < 8; ++r) A[pad(d + 8 * r)] = v[r];
    }
    __syncthreads();
    // stage 3: R=8, Ns=64, A -> B; w^r = e^{-i pi (t&63) r / 256}
    {
        #pragma unroll
        for (int r = 0; r < 8; ++r) v[r] = A[pad(t + 256 * r)];
        const float a = -(float)M_PI / 256.0f * (float)(t & 63);
        float2 w1 = sc(a), w2 = sc(2.0f * a), w4 = sc(4.0f * a);
        float2 w3 = cmul(w1, w2), w5 = cmul(w1, w4), w6 = cmul(w2, w4);
        float2 w7 = cmul(w3, w4);
        v[1] = cmul(v[1], w1); v[2] = cmul(v[2], w2); v[3] = cmul(v[3], w3);
        v[4] = cmul(v[4], w4); v[5] = cmul(v[5], w5); v[6] = cmul(v[6], w6);
        v[7] = cmul(v[7], w7);
        dft8(v);
        const int d = ((t >> 6) << 9) + (t & 63);
        #pragma unroll
        for (int r = 0; r < 8; ++r) B[pad(d + 64 * r)] = v[r];
    }
    __syncthreads();
    // stage 4: R=4, Ns=512, B -> A; w^r = e^{-i pi j r / 1024}
    #pragma unroll
    for (int h = 0; h < 2; ++h) {
        const int j = t + 256 * h;
        float2 u[4];
        #pragma unroll
        for (int r = 0; r < 4; ++r) u[r] = B[pad(j + 512 * r)];
        const float a = -(float)M_PI / 1024.0f * (float)j;
        float2 w1 = sc(a), w2 = sc(2.0f * a);
        float2 w3 = cmul(w1, w2);
        u[1] = cmul(u[1], w1);
        u[2] = cmul(u[2], w2);
        u[3] = cmul(u[3], w3);
        dft4(u);
        #pragma unroll
        for (int r = 0; r < 4; ++r) A[pad(j + 512 * r)] = u[r];
    }
    __syncthreads();

    // epilogue: rfft untangle + DCT twiddle; uu = e^{-i pi k / 2048}
    const float2* __restrict__ ek = (const float2*)expk;
    float* __restrict__ dst = out + (size_t)row * NFULL;
    #pragma unroll
    for (int i = 0; i < 8; ++i) {
        const int k = t + T * i;
        if (k == 0) {
            float2 z0 = A[pad(0)];
            dst[0]  = ek[0].x * (z0.x + z0.y);
            dst[NH] = ek[NH].x * (z0.x - z0.y);
        } else {
            float2 Zk = A[pad(k)];
            float2 Zr = A[pad(NH - k)];
            float2 E = make_float2(0.5f * (Zk.x + Zr.x), 0.5f * (Zk.y - Zr.y));
            float2 O = make_float2(0.5f * (Zk.y + Zr.y), 0.5f * (Zr.x - Zk.x));
            float2 uu = sc(-(float)M_PI / 2048.0f * (float)k);
            float2 Y = make_float2(E.x + uu.x * O.x - uu.y * O.y,
                                   E.y + uu.x * O.y + uu.y * O.x);
            float2 wk = ek[k];
            dst[k] = wk.x * Y.x - wk.y * Y.y;
            float2 wn = ek[NFULL - k];
            dst[NFULL - k] = wn.x * Y.x + wn.y * Y.y;
        }
    }
}

// 32x32 LDS-tiled transpose
__global__ __launch_bounds__(256) void transpose4k(const float* __restrict__ in,
                                                   float* __restrict__ out) {
    __shared__ float tile[32][33];
    const int x0 = blockIdx.x * 32;
    const int y0 = blockIdx.y * 32;
    const int tx = threadIdx.x & 31;
    const int ty = threadIdx.x >> 5;

    #pragma unroll
    for (int i = 0; i < 32; i += 8)
        tile[ty + i][tx] = in[(size_t)(y0 + ty + i) * NFULL + (x0 + tx)];
    __syncthreads();
    #pragma unroll
    for (int i = 0; i < 32; i += 8)
        out[(size_t)(x0 + ty + i) * NFULL + (y0 + tx)] = tile[tx][ty + i];
}

extern "C" void kernel_launch(void* const* d_in, const int* in_sizes, int n_in,
                              void* d_out, int out_size, void* d_ws, size_t ws_size,
                              hipStream_t stream) {
    const float* x     = (const float*)d_in[0];
    const float* expkM = (const float*)d_in[1];
    const float* expkN = (const float*)d_in[2];
    float* out = (float*)d_out;
    float* ws1 = (float*)d_ws;

    dct_rows_rfft<<<NFULL, T, 0, stream>>>(x, expkN, ws1);
    transpose4k<<<dim3(128, 128), 256, 0, stream>>>(ws1, out);
    dct_rows_rfft<<<NFULL, T, 0, stream>>>(out, expkM, ws1);
    transpose4k<<<dim3(128, 128), 256, 0, stream>>>(ws1, out);
}